// Round 5
// baseline (111.413 us; speedup 1.0000x reference)
//
#include <hip/hip_runtime.h>

// Radon transform: data (1,1,512,512) f32, angles (256,) f32 -> out (1,1,256,512) f32.
// Block = (angle, 64-col x-chunk), 512 threads (8 waves). Per 64-row y-chunk, stage
// the rotated patch's bbox (<=92x92) from a zero-padded image copy (d_ws) into LDS
// via global_load_lds width=16 (fixed 12 rows/wave, incremental addresses), then
// bilinear-sample from LDS with packed-fp32 blends. Compile-time LDS stride
// (95 if c>=0 else 97) folds both tap-pairs into two ds_read2_b32 from one base
// and keeps the per-lane bank step |c +- s| in [1, 1.414] -> ~conflict-free.

#define HH 512
#define WW 512
#define NA 256
#define XC 64
#define YC 64
#define NXC 8
#define NYC 8
#define NW 8                    // waves per block
#define RM 96                   // staged rows (12 per wave, fixed)
#define SM 97                   // max stride -> tile bytes = 96*97*4 = 37248 (4 blocks/CU)
#define PAD 112                 // >= 256*sqrt(2)-256+2
#define PW (WW + 2 * PAD)       // 736
#define PH (HH + 2 * PAD)       // 736

typedef float f32x2 __attribute__((ext_vector_type(2)));

__global__ __launch_bounds__(256) void pad_kernel(
    const float* __restrict__ img, float* __restrict__ P)
{
    const int c = blockIdx.x * 256 + threadIdx.x;
    const int r = blockIdx.y;
    if (c >= PW) return;
    const int gr = r - PAD, gc = c - PAD;
    float v = 0.0f;
    if ((unsigned)gr < (unsigned)HH && (unsigned)gc < (unsigned)WW)
        v = img[gr * WW + gc];
    P[r * PW + c] = v;
}

template <int S, bool PADDED>
__device__ __forceinline__ float radon_chunks(
    const float* __restrict__ src, float* __restrict__ tile,
    const float s, const float c, const int lane, const int wid, const int x0)
{
    const float u  = (float)(x0 + lane) + (0.5f - 256.0f);
    const float u0 = (float)x0 + (0.5f - 256.0f);
    const float u1 = u0 + 63.0f;

    // block-level hoisted bbox pieces (s >= 0 for angles in [0,pi))
    const float cu0 = c * u0, cu1 = c * u1;
    const float cumin = fminf(cu0, cu1), cumax = fmaxf(cu0, cu1);
    const float su0 = -s * u0, su1 = -s * u1;
    const float sumin = fminf(su0, su1), sumax = fmaxf(su0, su1);

    const float bcc = fmaf(c, u, 255.5f);    // global col coord at v=0 offset
    const float brc = fmaf(-s, u, 255.5f);   // global row coord

    const float* __restrict__ Porg =
        PADDED ? (src + PAD * PW + PAD) : src;   // origin-shifted padded base

    f32x2 accT = {0.0f, 0.0f}, accB = {0.0f, 0.0f};

    for (int yc = 0; yc < NYC; ++yc) {
        const float v0 = (float)(yc * YC) + (0.5f - 256.0f);
        const float v1 = v0 + 63.0f;

        const float sv0 = s * v0, sv1 = s * v1;           // s>=0: min=sv0,max=sv1
        const float cv0 = c * v0, cv1 = c * v1;
        const float cvmin = fminf(cv0, cv1), cvmax = fmaxf(cv0, cv1);

        const float cx_min = cumin + sv0 + 255.5f;
        const float cx_max = cumax + sv1 + 255.5f;
        const float rx_min = sumin + cvmin + 255.5f;
        const float rx_max = sumax + cvmax + 255.5f;

        const int c_lo = (int)floorf(cx_min);
        const int c_hi = (int)floorf(cx_max) + 1;
        const int r_lo = (int)floorf(rx_min);
        const int r_hi = (int)floorf(rx_max) + 1;

        // chunk entirely outside image -> contributes exactly 0 (block-uniform)
        if (c_lo > WW - 1 || c_hi < 0 || r_lo > HH - 1 || r_hi < 0) continue;

        __syncthreads();   // previous chunk's sampling must finish before overwrite

        if (PADDED) {
            // fixed 12 DMA rows per wave (rows 0..95); lanes 0..22 move 16B each
            // -> 368B per row (< S*4), extra rows/cols are garbage never sampled,
            // padded image guarantees all global addresses are in-buffer.
            if (lane < 23) {
                const float* g = Porg + (r_lo + wid) * PW + c_lo + lane * 4;
                int loff = wid * S;
#pragma unroll
                for (int k = 0; k < 12; ++k) {
                    __builtin_amdgcn_global_load_lds(
                        (const __attribute__((address_space(1))) void*)g,
                        (__attribute__((address_space(3))) void*)&tile[loff],
                        16, 0, 0);
                    g += NW * PW;
                    loff += NW * S;
                }
            }
        } else {
            // correctness-only fallback: bounds-checked scalar staging
            for (int r = wid; r < RM; r += NW) {
                const int gr = r_lo + r;
                const bool row_ok = ((unsigned)gr < (unsigned)HH);
                const float* __restrict__ rowp = src + gr * WW;
                for (int cc = lane; cc < 92; cc += 64) {
                    const int gc = c_lo + cc;
                    float v = 0.0f;
                    if (row_ok && (unsigned)gc < (unsigned)WW)
                        v = rowp[gc];
                    tile[r * S + cc] = v;
                }
            }
        }

        __syncthreads();

        // 8 samples per thread; coords advance by (s,c) per y -> fma with const i
        const float bc = bcc - (float)c_lo;
        const float br = brc - (float)r_lo;
        const float vyb = v0 + (float)(wid * 8);
        const float cx0 = fmaf(s, vyb, bc);
        const float rx0 = fmaf(c, vyb, br);

#pragma unroll
        for (int i = 0; i < 8; ++i) {
            const float cxl = fmaf(s, (float)i, cx0);   // local col coord >= 0
            const float rxl = fmaf(c, (float)i, rx0);   // local row coord >= 0
            const int ci = (int)cxl;                    // == floor (coords >= 0)
            const int ri = (int)rxl;
            const float wx1 = __builtin_amdgcn_fractf(cxl);
            const float wy1 = __builtin_amdgcn_fractf(rxl);
            const float wy0 = 1.0f - wy1;

            __builtin_assume(ri >= 0 && ri < RM - 1);
            __builtin_assume(ci >= 0 && ci < 92);
            const int ad = ri * S + ci;

            f32x2 vt, vb;                               // 2x ds_read2_b32, one base
            vt.x = tile[ad];     vt.y = tile[ad + 1];
            vb.x = tile[ad + S]; vb.y = tile[ad + S + 1];

            const f32x2 wx = {1.0f - wx1, wx1};
            accT = __builtin_elementwise_fma(wx * wy0, vt, accT);  // v_pk_fma_f32
            accB = __builtin_elementwise_fma(wx * wy1, vb, accB);
        }
    }

    return (accT.x + accT.y) + (accB.x + accB.y);
}

template <bool PADDED>
__global__ __launch_bounds__(512, 8) void radon_kernel(
    const float* __restrict__ src,   // PADDED ? padded image : raw image
    const float* __restrict__ angles, float* __restrict__ out)
{
    __shared__ float tile[RM * SM];   // 37248 B -> 4 blocks/CU

    const int tid  = threadIdx.x;
    const int lane = tid & 63;
    const int wid  = tid >> 6;

    const int a  = blockIdx.x >> 3;
    const int x0 = (blockIdx.x & 7) * XC;

    float s, c;
    sincosf(angles[a], &s, &c);

    // stride 95 (== -1 mod 32): bank step c+s ; stride 97 (== +1): bank step c-s.
    // s>=0, so pick per sign of c -> |step| in [1, 1.414]. Block-uniform branch.
    float acc;
    if (c >= 0.0f)
        acc = radon_chunks<95, PADDED>(src, tile, s, c, lane, wid, x0);
    else
        acc = radon_chunks<97, PADDED>(src, tile, s, c, lane, wid, x0);

    // reduce the 8 y-groups per column and store (each block owns its outputs)
    __syncthreads();
    tile[tid] = acc;
    __syncthreads();
    if (tid < 64) {
        float r = tile[tid];
#pragma unroll
        for (int k = 1; k < NW; ++k) r += tile[k * 64 + tid];
        out[a * WW + x0 + tid] = r;
    }
}

extern "C" void kernel_launch(void* const* d_in, const int* in_sizes, int n_in,
                              void* d_out, int out_size, void* d_ws, size_t ws_size,
                              hipStream_t stream) {
    const float* img    = (const float*)d_in[0];
    const float* angles = (const float*)d_in[1];
    float* out = (float*)d_out;
    float* P   = (float*)d_ws;

    const bool padded = (ws_size >= (size_t)PW * PH * sizeof(float));

    if (padded) {
        pad_kernel<<<dim3((PW + 255) / 256, PH), 256, 0, stream>>>(img, P);
        radon_kernel<true><<<dim3(NA * NXC), 512, 0, stream>>>(P, angles, out);
    } else {
        radon_kernel<false><<<dim3(NA * NXC), 512, 0, stream>>>(img, angles, out);
    }
}